// Round 1
// baseline (175.459 us; speedup 1.0000x reference)
//
#include <hip/hip_runtime.h>

#define NPTS 8192
#define NTOT 16384
#define DD 64
#define KNB 11
#define CAP 16

typedef __attribute__((ext_vector_type(8))) short short8;
typedef __attribute__((ext_vector_type(4))) float f32x4;

__device__ __forceinline__ unsigned short f2bf(float x) {
  union { float f; unsigned u; } v; v.f = x;
  unsigned r = v.u + 0x7FFFu + ((v.u >> 16) & 1u);
  return (unsigned short)(r >> 16);
}

// ---------------- K0: W12 = W1*W2, b12 = b1*W2 + b2 ----------------
__global__ __launch_bounds__(256) void k0_w12(
    const float* __restrict__ W1, const float* __restrict__ b1,
    const float* __restrict__ W2, const float* __restrict__ b2,
    float* __restrict__ W12, float* __restrict__ b12) {
  int t = blockIdx.x * 256 + threadIdx.x;
  if (t >= 4096) return;
  int d = t >> 6, e = t & 63;
  float s = 0.f;
  for (int kk = 0; kk < 64; ++kk) s = fmaf(W1[d * 64 + kk], W2[kk * 64 + e], s);
  W12[t] = s;
  if (d == 0) {
    float sb = b2[e];
    for (int kk = 0; kk < 64; ++kk) sb = fmaf(b1[kk], W2[kk * 64 + e], sb);
    b12[e] = sb;
  }
}

// ---------------- K1: f = p^T * W12 + b12 ; sq ; bf16 copy ----------------
__global__ __launch_bounds__(64) void k1_encode(
    const float* __restrict__ p,      // [2][64][NPTS]
    const float* __restrict__ W12,    // [64][64]
    const float* __restrict__ b12,    // [64]
    float* __restrict__ f32f,         // [NTOT][64]
    unsigned short* __restrict__ fbf, // [NTOT][64]
    float* __restrict__ sq) {         // [NTOT]
  __shared__ float sW[64 * 64];
  __shared__ float sb[64];
  for (int j = threadIdx.x; j < 4096; j += 64) sW[j] = W12[j];
  if (threadIdx.x < 64) sb[threadIdx.x] = b12[threadIdx.x];
  __syncthreads();

  int P = blockIdx.x * 64 + threadIdx.x;   // 0..16383
  int b = P >> 13, n = P & (NPTS - 1);
  const float* pb = p + (size_t)b * 64 * NPTS + n;

  float f[64];
#pragma unroll
  for (int e = 0; e < 64; ++e) f[e] = sb[e];
  for (int d = 0; d < 64; ++d) {
    float pd = pb[(size_t)d * NPTS];
    const f32x4* wrow = (const f32x4*)(sW + d * 64);
#pragma unroll
    for (int e4 = 0; e4 < 16; ++e4) {
      f32x4 wv = wrow[e4];
      f[e4 * 4 + 0] = fmaf(pd, wv[0], f[e4 * 4 + 0]);
      f[e4 * 4 + 1] = fmaf(pd, wv[1], f[e4 * 4 + 1]);
      f[e4 * 4 + 2] = fmaf(pd, wv[2], f[e4 * 4 + 2]);
      f[e4 * 4 + 3] = fmaf(pd, wv[3], f[e4 * 4 + 3]);
    }
  }
  // sq: sequential fmaf chain (MUST match k3_refine's dot order for exact self-d2=0)
  float s = 0.f;
#pragma unroll
  for (int e = 0; e < 64; ++e) s = fmaf(f[e], f[e], s);
  sq[P] = s;

  f32x4* o4 = (f32x4*)(f32f + (size_t)P * 64);
#pragma unroll
  for (int j = 0; j < 16; ++j) {
    f32x4 v; v[0] = f[4 * j]; v[1] = f[4 * j + 1]; v[2] = f[4 * j + 2]; v[3] = f[4 * j + 3];
    o4[j] = v;
  }
  unsigned* ob = (unsigned*)(fbf + (size_t)P * 64);
#pragma unroll
  for (int j = 0; j < 32; ++j) {
    unsigned lo = f2bf(f[2 * j]);
    unsigned hi = f2bf(f[2 * j + 1]);
    ob[j] = lo | (hi << 16);
  }
}

// ---------------- K2: bf16 MFMA Gram + threshold (d2<8) candidate capture ----------------
__global__ __launch_bounds__(256, 2) void k2_gram_select(
    const unsigned short* __restrict__ fbf, // [NTOT][64]
    const float* __restrict__ sq,           // [NTOT]
    unsigned* __restrict__ cnt,             // [NTOT]
    unsigned* __restrict__ cand) {          // [NTOT][CAP]
  int bid = blockIdx.x;          // 512 blocks = 2 batches * 32 bands * 8 segs
  int b = bid >> 8;
  int rem = bid & 255;
  int band = rem >> 3;
  int seg = rem & 7;
  int lane = threadIdx.x & 63;
  int wave = threadIdx.x >> 6;
  int rowbase = band * 256 + wave * 64;
  const unsigned short* fb = fbf + (size_t)b * NPTS * 64;
  const float* sqb = sq + b * NPTS;

  int arow = lane & 15;
  int akoff = (lane >> 4) * 8;

  // A fragments: 4 row-tiles x 2 k-steps (resident across the col loop)
  short8 afrag[4][2];
#pragma unroll
  for (int tr = 0; tr < 4; ++tr) {
    const unsigned short* base = fb + (size_t)(rowbase + tr * 16 + arow) * 64 + akoff;
    afrag[tr][0] = *(const short8*)(base);
    afrag[tr][1] = *(const short8*)(base + 32);
  }
  // row thresholds: ur = 0.5*sq[r] - 4  (d2<8  <=>  g > ur + vc)
  float ur[4][4], umin[4];
#pragma unroll
  for (int tr = 0; tr < 4; ++tr) {
    int r0 = rowbase + tr * 16 + ((lane >> 4) << 2);
    f32x4 s4 = *(const f32x4*)(sqb + r0);
    ur[tr][0] = 0.5f * s4[0] - 4.f;
    ur[tr][1] = 0.5f * s4[1] - 4.f;
    ur[tr][2] = 0.5f * s4[2] - 4.f;
    ur[tr][3] = 0.5f * s4[3] - 4.f;
    umin[tr] = fminf(fminf(ur[tr][0], ur[tr][1]), fminf(ur[tr][2], ur[tr][3]));
  }

  int c0 = seg * 1024;
  for (int cc = 0; cc < 16; ++cc, c0 += 64) {
    short8 bfr[4][2];
    float vc[4];
#pragma unroll
    for (int tc = 0; tc < 4; ++tc) {
      int cpt = c0 + tc * 16 + arow;
      const unsigned short* base = fb + (size_t)cpt * 64 + akoff;
      bfr[tc][0] = *(const short8*)(base);
      bfr[tc][1] = *(const short8*)(base + 32);
      vc[tc] = 0.5f * sqb[cpt];
    }
    f32x4 acc[4][4];
#pragma unroll
    for (int tr = 0; tr < 4; ++tr)
#pragma unroll
      for (int tc = 0; tc < 4; ++tc) {
        f32x4 z = {0.f, 0.f, 0.f, 0.f};
        f32x4 t0 = __builtin_amdgcn_mfma_f32_16x16x32_bf16(afrag[tr][0], bfr[tc][0], z, 0, 0, 0);
        acc[tr][tc] = __builtin_amdgcn_mfma_f32_16x16x32_bf16(afrag[tr][1], bfr[tc][1], t0, 0, 0, 0);
      }
    // coarse scan: max over tile's 4 acc vs (umin[tr]+vc[tc])
    float cm = -1.f;
#pragma unroll
    for (int tr = 0; tr < 4; ++tr)
#pragma unroll
      for (int tc = 0; tc < 4; ++tc) {
        f32x4 a = acc[tr][tc];
        float m = fmaxf(fmaxf(a[0], a[1]), fmaxf(a[2], a[3]));
        cm = fmaxf(cm, m - (umin[tr] + vc[tc]));
      }
    if (__ballot(cm > 0.f)) {
#pragma unroll
      for (int tr = 0; tr < 4; ++tr)
#pragma unroll
        for (int tc = 0; tc < 4; ++tc)
#pragma unroll
          for (int rg = 0; rg < 4; ++rg) {
            float g = acc[tr][tc][rg];
            float t = ur[tr][rg] + vc[tc];
            if (g > t) {
              float d2 = 2.f * (t - g) + 8.f;   // = sq_r + sq_c - 2g  (< 8)
              int rowpt = rowbase + tr * 16 + ((lane >> 4) << 2) + rg;
              int colpt = c0 + tc * 16 + arow;
              int gr = b * NPTS + rowpt;
              union { float f; unsigned u; } cv; cv.f = d2 + 16.f;  // positive -> monotonic bits
              unsigned key = (cv.u & 0xFFFFE000u) | (unsigned)colpt;
              unsigned slot = atomicAdd(&cnt[gr], 1u);
              if (slot < CAP) cand[gr * CAP + slot] = key;
            }
          }
    }
  }
}

// ---------------- K3: sort candidates, refine weights in exact f32 ----------------
__global__ __launch_bounds__(64) void k3_refine(
    const float* __restrict__ f32f, const float* __restrict__ sq,
    const unsigned* __restrict__ cnt, const unsigned* __restrict__ cand,
    float* __restrict__ W, int* __restrict__ IDX) {
  int r = blockIdx.x * 64 + threadIdx.x;  // 0..16383
  int b = r >> 13;
  unsigned count = cnt[r];
  if (count > CAP) count = CAP;

  unsigned k[CAP];
#pragma unroll
  for (int j = 0; j < CAP; ++j)
    k[j] = (j < (int)count) ? cand[r * CAP + j] : 0xFFFFFFFFu;
  // full bubble sort network (static indices -> registers)
#pragma unroll
  for (int a = 0; a < CAP - 1; ++a)
#pragma unroll
    for (int c = 0; c < CAP - 1; ++c) {
      unsigned lo = min(k[c], k[c + 1]);
      unsigned hi = max(k[c], k[c + 1]);
      k[c] = lo; k[c + 1] = hi;
    }

  float fr[64];
  const f32x4* fr4 = (const f32x4*)(f32f + (size_t)r * 64);
#pragma unroll
  for (int j = 0; j < 16; ++j) {
    f32x4 v = fr4[j];
    fr[4 * j] = v[0]; fr[4 * j + 1] = v[1]; fr[4 * j + 2] = v[2]; fr[4 * j + 3] = v[3];
  }
  float sqr = sq[r];
  int nsel = (int)count < KNB ? (int)count : KNB;
#pragma unroll
  for (int kk = 0; kk < KNB; ++kk) {
    float w = 0.f;
    int gi = r;
    if (kk < nsel) {
      int col = (int)(k[kk] & 8191u);
      gi = b * NPTS + col;
      const float* fm = f32f + (size_t)gi * 64;
      float dot = 0.f;
#pragma unroll
      for (int d = 0; d < 64; ++d) dot = fmaf(fr[d], fm[d], dot);  // same order as sq chain
      float d2 = sqr + sq[gi] - 2.f * dot;  // self -> exactly 0 -> w = 1
      w = expf(-d2);
    }
    W[r * KNB + kk] = w;
    IDX[r * KNB + kk] = gi;
  }
}

// ---------------- K4: one mean-field iteration (+ writes sigmoid to out) ----------------
__global__ __launch_bounds__(256) void k4_iter(
    const float* __restrict__ logits, const float* __restrict__ uin,
    const float* __restrict__ W, const int* __restrict__ IDX,
    float* __restrict__ uout, float* __restrict__ out) {
  int i = blockIdx.x * 256 + threadIdx.x;  // 0..16383
  float msg = 0.f;
#pragma unroll
  for (int kk = 0; kk < KNB; ++kk) {
    float w = W[i * KNB + kk];
    int m = IDX[i * KNB + kk];
    float q = 1.f / (1.f + expf(-uin[m]));
    msg = fmaf(w, q, msg);
  }
  float u = logits[i] - msg;
  uout[i] = u;
  out[i] = 1.f / (1.f + expf(-u));
}

// ---------------- launch ----------------
extern "C" void kernel_launch(void* const* d_in, const int* in_sizes, int n_in,
                              void* d_out, int out_size, void* d_ws, size_t ws_size,
                              hipStream_t stream) {
  const float* logits = (const float*)d_in[0]; // [2][8192]
  const float* p      = (const float*)d_in[1]; // [2][64][8192]
  const float* W1     = (const float*)d_in[2];
  const float* b1     = (const float*)d_in[3];
  const float* W2     = (const float*)d_in[4];
  const float* b2     = (const float*)d_in[5];
  float* out = (float*)d_out;                  // [2][8192]

  char* ws = (char*)d_ws;
  float* W12 = (float*)ws;                              // 4096 f
  float* b12 = W12 + 4096;                              // 64 f
  float* f32f = b12 + 64;                               // NTOT*64 f
  unsigned short* fbf = (unsigned short*)(f32f + (size_t)NTOT * 64); // NTOT*64 bf16
  float* sq = (float*)(fbf + (size_t)NTOT * 64);        // NTOT f
  unsigned* cnt = (unsigned*)(sq + NTOT);               // NTOT u32
  unsigned* cand = cnt + NTOT;                          // NTOT*CAP u32
  float* Wbuf = (float*)(cand + (size_t)NTOT * CAP);    // NTOT*11 f
  int* IDX = (int*)(Wbuf + (size_t)NTOT * KNB);         // NTOT*11 i32
  float* u_a = (float*)(IDX + (size_t)NTOT * KNB);      // NTOT f
  float* u_b = u_a + NTOT;                              // NTOT f

  hipMemsetAsync(cnt, 0, NTOT * sizeof(unsigned), stream);

  k0_w12<<<16, 256, 0, stream>>>(W1, b1, W2, b2, W12, b12);
  k1_encode<<<256, 64, 0, stream>>>(p, W12, b12, f32f, fbf, sq);
  k2_gram_select<<<512, 256, 0, stream>>>(fbf, sq, cnt, cand);
  k3_refine<<<256, 64, 0, stream>>>(f32f, sq, cnt, cand, Wbuf, IDX);

  k4_iter<<<64, 256, 0, stream>>>(logits, logits, Wbuf, IDX, u_a, out);
  k4_iter<<<64, 256, 0, stream>>>(logits, u_a, Wbuf, IDX, u_b, out);
  k4_iter<<<64, 256, 0, stream>>>(logits, u_b, Wbuf, IDX, u_a, out);
  k4_iter<<<64, 256, 0, stream>>>(logits, u_a, Wbuf, IDX, u_b, out);
  k4_iter<<<64, 256, 0, stream>>>(logits, u_b, Wbuf, IDX, u_a, out);
}

// Round 2
// 168.640 us; speedup vs baseline: 1.0404x; 1.0404x over previous
//
#include <hip/hip_runtime.h>

#define NPTS 8192
#define NTOT 16384
#define KNB 11
#define CAP 16
#define K4BLK 64

typedef __attribute__((ext_vector_type(8))) short short8;
typedef __attribute__((ext_vector_type(4))) float f32x4;

__device__ __forceinline__ unsigned short f2bf(float x) {
  union { float f; unsigned u; } v; v.f = x;
  unsigned r = v.u + 0x7FFFu + ((v.u >> 16) & 1u);
  return (unsigned short)(r >> 16);
}

// ---------------- K0: W12 = W1*W2, b12 = b1*W2 + b2 ; zero grid-barrier ----------------
__global__ __launch_bounds__(256) void k0_w12(
    const float* __restrict__ W1, const float* __restrict__ b1,
    const float* __restrict__ W2, const float* __restrict__ b2,
    float* __restrict__ W12, float* __restrict__ b12, unsigned* __restrict__ bar) {
  int t = blockIdx.x * 256 + threadIdx.x;
  if (t == 0) *bar = 0u;
  if (t >= 4096) return;
  int d = t >> 6, e = t & 63;
  float s = 0.f;
  for (int kk = 0; kk < 64; ++kk) s = fmaf(W1[d * 64 + kk], W2[kk * 64 + e], s);
  W12[t] = s;
  if (d == 0) {
    float sb = b2[e];
    for (int kk = 0; kk < 64; ++kk) sb = fmaf(b1[kk], W2[kk * 64 + e], sb);
    b12[e] = sb;
  }
}

// ---------------- K1: f = p^T*W12 + b12 ; sq ; bf16 copy ; zero cnt ----------------
// block = 64 points x 4 e-slices (one wave per slice). W12 accessed wave-uniformly -> s_load.
__global__ __launch_bounds__(256) void k1_encode(
    const float* __restrict__ p,      // [2][64][NPTS]
    const float* __restrict__ W12,    // [64][64]
    const float* __restrict__ b12,    // [64]
    float* __restrict__ f32f,         // [NTOT][64]
    unsigned short* __restrict__ fbf, // [NTOT][64]
    float* __restrict__ sq,           // [NTOT]
    unsigned* __restrict__ cnt) {     // [NTOT]
  __shared__ float sPart[4][64];
  int t = threadIdx.x, lane = t & 63, w = t >> 6;
  int gid = blockIdx.x * 256 + t;
  if (gid < NTOT) cnt[gid] = 0u;

  int base = blockIdx.x * 64;              // 256 blocks -> 16384 points
  int b = base >> 13, n0 = base & (NPTS - 1);
  const float* pb = p + (size_t)b * 64 * NPTS + n0 + lane;
  int e0 = __builtin_amdgcn_readfirstlane(w) * 16;   // wave-uniform -> scalar path

  float f[16];
#pragma unroll
  for (int j = 0; j < 16; ++j) f[j] = b12[e0 + j];

#pragma unroll 4
  for (int d = 0; d < 64; ++d) {
    float pd = pb[(size_t)d * NPTS];
#pragma unroll
    for (int j = 0; j < 16; ++j)
      f[j] = fmaf(pd, W12[d * 64 + e0 + j], f[j]);
  }

  float s = 0.f;
#pragma unroll
  for (int j = 0; j < 16; ++j) s = fmaf(f[j], f[j], s);
  sPart[w][lane] = s;
  __syncthreads();
  if (w == 0) {
    float tot = ((sPart[0][lane] + sPart[1][lane]) + sPart[2][lane]) + sPart[3][lane];
    sq[base + lane] = tot;
  }

  f32x4* o4 = (f32x4*)(f32f + (size_t)(base + lane) * 64 + e0);
#pragma unroll
  for (int jj = 0; jj < 4; ++jj) {
    f32x4 v; v[0] = f[4 * jj]; v[1] = f[4 * jj + 1]; v[2] = f[4 * jj + 2]; v[3] = f[4 * jj + 3];
    o4[jj] = v;
  }
  unsigned* ob = (unsigned*)(fbf + (size_t)(base + lane) * 64 + e0);
#pragma unroll
  for (int jj = 0; jj < 8; ++jj) {
    unsigned lo = f2bf(f[2 * jj]);
    unsigned hi = f2bf(f[2 * jj + 1]);
    ob[jj] = lo | (hi << 16);
  }
}

// ---------------- K2: LDS-staged bf16 MFMA Gram + threshold (d2<8) capture ----------------
// 1024 blocks = 2 batches * 32 bands * 16 segs. Block: 4 waves x 64 rows = 256 rows,
// cols: seg*512 .. +512 in 8 tiles of 64, staged in double-buffered swizzled LDS.
__global__ __launch_bounds__(256, 4) void k2_gram_select(
    const unsigned short* __restrict__ fbf, // [NTOT][64]
    const float* __restrict__ sq,           // [NTOT]
    unsigned* __restrict__ cnt,             // [NTOT]
    unsigned* __restrict__ cand) {          // [NTOT][CAP]
  __shared__ uint4 sB[2][512];              // 2 x 8KB, 16B chunks, XOR-swizzled
  int bid = blockIdx.x;
  int b = bid >> 9;
  int rem = bid & 511;
  int band = rem >> 4;
  int seg = rem & 15;
  int t = threadIdx.x;
  int lane = t & 63, wave = t >> 6;
  int rowbase = band * 256 + wave * 64;
  const unsigned short* fb = fbf + (size_t)b * NPTS * 64;
  const float* sqb = sq + b * NPTS;
  const uint4* gsrc = (const uint4*)fb + seg * 4096;  // seg base in 16B chunks

  // prologue: issue loads for tile 0
  uint4 v0 = gsrc[t];
  uint4 v1 = gsrc[t + 256];
  // swizzled LDS chunk indices for this thread's two staged chunks
  int r0 = t >> 3;
  int l0 = r0 * 8 + ((t & 7) ^ (r0 & 7));
  int t2 = t + 256;
  int r1 = t2 >> 3;
  int l1 = r1 * 8 + ((t2 & 7) ^ (r1 & 7));

  int arow = lane & 15;
  int q = lane >> 4;
  int akoff = q * 8;

  short8 afrag[4][2];
#pragma unroll
  for (int tr = 0; tr < 4; ++tr) {
    const unsigned short* basep = fb + (size_t)(rowbase + tr * 16 + arow) * 64 + akoff;
    afrag[tr][0] = *(const short8*)(basep);
    afrag[tr][1] = *(const short8*)(basep + 32);
  }
  float ur[4][4], umin[4];
#pragma unroll
  for (int tr = 0; tr < 4; ++tr) {
    int rr = rowbase + tr * 16 + (q << 2);
    f32x4 s4 = *(const f32x4*)(sqb + rr);
    ur[tr][0] = 0.5f * s4[0] - 4.f;
    ur[tr][1] = 0.5f * s4[1] - 4.f;
    ur[tr][2] = 0.5f * s4[2] - 4.f;
    ur[tr][3] = 0.5f * s4[3] - 4.f;
    umin[tr] = fminf(fminf(ur[tr][0], ur[tr][1]), fminf(ur[tr][2], ur[tr][3]));
  }

  for (int cc = 0; cc < 8; ++cc) {
    // write staged tile (vmcnt for loads issued a full compute-phase ago)
    uint4* dst = sB[cc & 1];
    dst[l0] = v0;
    dst[l1] = v1;
    __syncthreads();
    // issue next tile's global loads immediately
    if (cc < 7) {
      const uint4* g2 = gsrc + (cc + 1) * 512;
      v0 = g2[t];
      v1 = g2[t + 256];
    }
    int c0 = seg * 512 + cc * 64;
    // prefetch column sq values
    float vcs[4];
#pragma unroll
    for (int tc = 0; tc < 4; ++tc) vcs[tc] = 0.5f * sqb[c0 + tc * 16 + arow];

    const uint4* src = sB[cc & 1];
#pragma unroll
    for (int tc = 0; tc < 4; ++tc) {
      int rl = tc * 16 + arow;
      int sx = rl & 7;
      short8 b0 = *(const short8*)&src[rl * 8 + (q ^ sx)];
      short8 b1 = *(const short8*)&src[rl * 8 + ((q + 4) ^ sx)];
      float vct = vcs[tc];
      f32x4 acc[4];
      float cm = -1.f;
#pragma unroll
      for (int tr = 0; tr < 4; ++tr) {
        f32x4 z = {0.f, 0.f, 0.f, 0.f};
        f32x4 t0 = __builtin_amdgcn_mfma_f32_16x16x32_bf16(afrag[tr][0], b0, z, 0, 0, 0);
        acc[tr] = __builtin_amdgcn_mfma_f32_16x16x32_bf16(afrag[tr][1], b1, t0, 0, 0, 0);
      }
#pragma unroll
      for (int tr = 0; tr < 4; ++tr) {
        f32x4 a = acc[tr];
        float m = fmaxf(fmaxf(a[0], a[1]), fmaxf(a[2], a[3]));
        cm = fmaxf(cm, m - (umin[tr] + vct));
      }
      if (__ballot(cm > 0.f)) {
#pragma unroll
        for (int tr = 0; tr < 4; ++tr)
#pragma unroll
          for (int rg = 0; rg < 4; ++rg) {
            float g = acc[tr][rg];
            float th = ur[tr][rg] + vct;
            if (g > th) {
              float d2 = 2.f * (th - g) + 8.f;   // = sq_r + sq_c - 2g  (< 8)
              int rowpt = rowbase + tr * 16 + (q << 2) + rg;
              int colpt = c0 + tc * 16 + arow;
              int gr = b * NPTS + rowpt;
              union { float f; unsigned u; } cv; cv.f = d2 + 16.f;  // positive -> monotonic bits
              unsigned key = (cv.u & 0xFFFFE000u) | (unsigned)colpt;
              unsigned slot = atomicAdd(&cnt[gr], 1u);
              if (slot < CAP) cand[gr * CAP + slot] = key;
            }
          }
      }
    }
  }
}

// ---------------- K3: refine (only rows with >1 candidate) ----------------
__global__ __launch_bounds__(256) void k3_refine(
    const float* __restrict__ f32f, const float* __restrict__ sq,
    const unsigned* __restrict__ cnt, const unsigned* __restrict__ cand,
    float* __restrict__ W, int* __restrict__ IDX) {
  int r = blockIdx.x * 256 + threadIdx.x;  // 64 blocks
  int b = r >> 13;
  unsigned count = cnt[r];
  if (count > CAP) count = CAP;
  if (count <= 1) return;                  // self-only: K4 fast path handles it

  unsigned k[CAP];
#pragma unroll
  for (int j = 0; j < CAP; ++j)
    k[j] = (j < (int)count) ? cand[r * CAP + j] : 0xFFFFFFFFu;
#pragma unroll
  for (int a = 0; a < CAP - 1; ++a)
#pragma unroll
    for (int c = 0; c < CAP - 1; ++c) {
      unsigned lo = min(k[c], k[c + 1]);
      unsigned hi = max(k[c], k[c + 1]);
      k[c] = lo; k[c + 1] = hi;
    }

  float fr[64];
  const f32x4* fr4 = (const f32x4*)(f32f + (size_t)r * 64);
#pragma unroll
  for (int j = 0; j < 16; ++j) {
    f32x4 v = fr4[j];
    fr[4 * j] = v[0]; fr[4 * j + 1] = v[1]; fr[4 * j + 2] = v[2]; fr[4 * j + 3] = v[3];
  }
  float sqr = sq[r];
  int nsel = (int)count < KNB ? (int)count : KNB;
#pragma unroll
  for (int kk = 0; kk < KNB; ++kk) {
    float w = 0.f;
    int gi = r;
    if (kk < nsel) {
      int col = (int)(k[kk] & 8191u);
      gi = b * NPTS + col;
      const float* fm = f32f + (size_t)gi * 64;
      float dot = 0.f;
#pragma unroll
      for (int d = 0; d < 64; ++d) dot = fmaf(fr[d], fm[d], dot);
      float d2 = sqr + sq[gi] - 2.f * dot;
      w = expf(-d2);
    }
    W[r * KNB + kk] = w;
    IDX[r * KNB + kk] = gi;
  }
}

// ---------------- K4: 5 fused mean-field iterations with software grid barrier ----------------
__global__ __launch_bounds__(256) void k4_fused(
    const float* __restrict__ logits, const unsigned* __restrict__ cnt,
    const float* __restrict__ W, const int* __restrict__ IDX,
    float* __restrict__ qA, float* __restrict__ qB,
    float* __restrict__ out, unsigned* __restrict__ bar) {
  int i = blockIdx.x * 256 + threadIdx.x;   // 64 blocks x 256 = 16384
  float lg = logits[i];
  unsigned c = cnt[i];
  float u = lg;
  float qv = 1.f / (1.f + expf(-u));
  const int* idxp = IDX + (size_t)i * KNB;
  const float* wp = W + (size_t)i * KNB;

  for (int it = 0; it < 5; ++it) {
    float* qw = (it & 1) ? qB : qA;
    qw[i] = qv;
    __threadfence();
    __syncthreads();
    if (threadIdx.x == 0) {
      __hip_atomic_fetch_add(bar, 1u, __ATOMIC_ACQ_REL, __HIP_MEMORY_SCOPE_AGENT);
      unsigned target = (unsigned)K4BLK * (unsigned)(it + 1);
      while (__hip_atomic_load(bar, __ATOMIC_ACQUIRE, __HIP_MEMORY_SCOPE_AGENT) < target) {
        __builtin_amdgcn_s_sleep(1);
      }
    }
    __syncthreads();
    float msg;
    if (c == 1u) {
      msg = qv;                              // self weight is exactly 1
    } else {
      msg = 0.f;
      const float* qr = qw;
#pragma unroll
      for (int kk = 0; kk < KNB; ++kk)
        msg = fmaf(wp[kk], qr[idxp[kk]], msg);
    }
    u = lg - msg;
    qv = 1.f / (1.f + expf(-u));
  }
  out[i] = qv;
}

// ---------------- launch ----------------
extern "C" void kernel_launch(void* const* d_in, const int* in_sizes, int n_in,
                              void* d_out, int out_size, void* d_ws, size_t ws_size,
                              hipStream_t stream) {
  const float* logits = (const float*)d_in[0]; // [2][8192]
  const float* p      = (const float*)d_in[1]; // [2][64][8192]
  const float* W1     = (const float*)d_in[2];
  const float* b1     = (const float*)d_in[3];
  const float* W2     = (const float*)d_in[4];
  const float* b2     = (const float*)d_in[5];
  float* out = (float*)d_out;                  // [2][8192]

  char* ws = (char*)d_ws;
  float* W12 = (float*)ws;                              // 4096 f
  float* b12 = W12 + 4096;                              // 64 f
  float* f32f = b12 + 64;                               // NTOT*64 f
  unsigned short* fbf = (unsigned short*)(f32f + (size_t)NTOT * 64); // NTOT*64 bf16
  float* sq = (float*)(fbf + (size_t)NTOT * 64);        // NTOT f
  unsigned* cnt = (unsigned*)(sq + NTOT);               // NTOT u32
  unsigned* cand = cnt + NTOT;                          // NTOT*CAP u32
  float* Wbuf = (float*)(cand + (size_t)NTOT * CAP);    // NTOT*11 f
  int* IDX = (int*)(Wbuf + (size_t)NTOT * KNB);         // NTOT*11 i32
  float* qA = (float*)(IDX + (size_t)NTOT * KNB);       // NTOT f
  float* qB = qA + NTOT;                                // NTOT f
  unsigned* bar = (unsigned*)(qB + NTOT);               // 1 u32

  k0_w12<<<16, 256, 0, stream>>>(W1, b1, W2, b2, W12, b12, bar);
  k1_encode<<<256, 256, 0, stream>>>(p, W12, b12, f32f, fbf, sq, cnt);
  k2_gram_select<<<1024, 256, 0, stream>>>(fbf, sq, cnt, cand);
  k3_refine<<<64, 256, 0, stream>>>(f32f, sq, cnt, cand, Wbuf, IDX);
  k4_fused<<<64, 256, 0, stream>>>(logits, cnt, Wbuf, IDX, qA, qB, out, bar);
}

// Round 3
// 144.164 us; speedup vs baseline: 1.2171x; 1.1698x over previous
//
#include <hip/hip_runtime.h>

#define NPTS 8192
#define NTOT 16384
#define KNB 11
#define CAP 16

typedef __attribute__((ext_vector_type(8))) short short8;
typedef __attribute__((ext_vector_type(4))) float f32x4;

__device__ __forceinline__ unsigned short f2bf(float x) {
  union { float f; unsigned u; } v; v.f = x;
  unsigned r = v.u + 0x7FFFu + ((v.u >> 16) & 1u);
  return (unsigned short)(r >> 16);
}

// ---------------- K0: W12 = W1*W2, b12 = b1*W2 + b2 ----------------
__global__ __launch_bounds__(256) void k0_w12(
    const float* __restrict__ W1, const float* __restrict__ b1,
    const float* __restrict__ W2, const float* __restrict__ b2,
    float* __restrict__ W12, float* __restrict__ b12) {
  int t = blockIdx.x * 256 + threadIdx.x;
  if (t >= 4096) return;
  int d = t >> 6, e = t & 63;
  float s = 0.f;
  for (int kk = 0; kk < 64; ++kk) s = fmaf(W1[d * 64 + kk], W2[kk * 64 + e], s);
  W12[t] = s;
  if (d == 0) {
    float sb = b2[e];
    for (int kk = 0; kk < 64; ++kk) sb = fmaf(b1[kk], W2[kk * 64 + e], sb);
    b12[e] = sb;
  }
}

// ---------------- K1: f = p^T*W12 + b12 ; sq ; bf16 copy ; zero cnt ----------------
__global__ __launch_bounds__(256) void k1_encode(
    const float* __restrict__ p,      // [2][64][NPTS]
    const float* __restrict__ W12,    // [64][64]
    const float* __restrict__ b12,    // [64]
    float* __restrict__ f32f,         // [NTOT][64]
    unsigned short* __restrict__ fbf, // [NTOT][64]
    float* __restrict__ sq,           // [NTOT]
    unsigned* __restrict__ cnt) {     // [NTOT]
  __shared__ float sPart[4][64];
  int t = threadIdx.x, lane = t & 63, w = t >> 6;
  int gid = blockIdx.x * 256 + t;
  if (gid < NTOT) cnt[gid] = 0u;

  int base = blockIdx.x * 64;              // 256 blocks -> 16384 points
  int b = base >> 13, n0 = base & (NPTS - 1);
  const float* pb = p + (size_t)b * 64 * NPTS + n0 + lane;
  int e0 = __builtin_amdgcn_readfirstlane(w) * 16;   // wave-uniform -> scalar path

  float f[16];
#pragma unroll
  for (int j = 0; j < 16; ++j) f[j] = b12[e0 + j];

#pragma unroll 8
  for (int d = 0; d < 64; ++d) {
    float pd = pb[(size_t)d * NPTS];
#pragma unroll
    for (int j = 0; j < 16; ++j)
      f[j] = fmaf(pd, W12[d * 64 + e0 + j], f[j]);
  }

  float s = 0.f;
#pragma unroll
  for (int j = 0; j < 16; ++j) s = fmaf(f[j], f[j], s);
  sPart[w][lane] = s;
  __syncthreads();
  if (w == 0) {
    float tot = ((sPart[0][lane] + sPart[1][lane]) + sPart[2][lane]) + sPart[3][lane];
    sq[base + lane] = tot;
  }

  f32x4* o4 = (f32x4*)(f32f + (size_t)(base + lane) * 64 + e0);
#pragma unroll
  for (int jj = 0; jj < 4; ++jj) {
    f32x4 v; v[0] = f[4 * jj]; v[1] = f[4 * jj + 1]; v[2] = f[4 * jj + 2]; v[3] = f[4 * jj + 3];
    o4[jj] = v;
  }
  unsigned* ob = (unsigned*)(fbf + (size_t)(base + lane) * 64 + e0);
#pragma unroll
  for (int jj = 0; jj < 8; ++jj) {
    unsigned lo = f2bf(f[2 * jj]);
    unsigned hi = f2bf(f[2 * jj + 1]);
    ob[jj] = lo | (hi << 16);
  }
}

// ---------------- K2: single-barrier LDS-panel bf16 MFMA Gram + threshold capture ----
// 2048 blocks = 2 batches * 32 bands * 32 segs. Block: 4 waves x 64 rows = 256 rows,
// cols: seg*256 .. +256 staged ONCE into swizzled LDS (32 KB), then pure LDS+MFMA.
__global__ __launch_bounds__(256) void k2_gram_select(
    const unsigned short* __restrict__ fbf, // [NTOT][64]
    const float* __restrict__ sq,           // [NTOT]
    unsigned* __restrict__ cnt,             // [NTOT]
    unsigned* __restrict__ cand) {          // [NTOT][CAP]
  __shared__ uint4 sB[2048];                // 32 KB, 16B chunks, XOR-swizzled
  int bid = blockIdx.x;
  int b = bid >> 10;
  int rem = bid & 1023;
  int band = rem >> 5;
  int seg = rem & 31;
  int t = threadIdx.x;
  int lane = t & 63, wave = t >> 6;
  int rowbase = band * 256 + wave * 64;
  const unsigned short* fb = fbf + (size_t)b * NPTS * 64;
  const float* sqb = sq + b * NPTS;

  // ---- prologue: issue ALL global loads, then one barrier ----
  const uint4* gsrc = (const uint4*)fb + seg * 2048;
  uint4 v[8];
#pragma unroll
  for (int k = 0; k < 8; ++k) v[k] = gsrc[t + k * 256];

  int arow = lane & 15;
  int q = lane >> 4;
  int akoff = q * 8;

  short8 afrag[4][2];
#pragma unroll
  for (int tr = 0; tr < 4; ++tr) {
    const unsigned short* basep = fb + (size_t)(rowbase + tr * 16 + arow) * 64 + akoff;
    afrag[tr][0] = *(const short8*)(basep);
    afrag[tr][1] = *(const short8*)(basep + 32);
  }
  float ur[4][4], umin[4];
#pragma unroll
  for (int tr = 0; tr < 4; ++tr) {
    int rr = rowbase + tr * 16 + (q << 2);
    f32x4 s4 = *(const f32x4*)(sqb + rr);
    ur[tr][0] = 0.5f * s4[0] - 4.f;
    ur[tr][1] = 0.5f * s4[1] - 4.f;
    ur[tr][2] = 0.5f * s4[2] - 4.f;
    ur[tr][3] = 0.5f * s4[3] - 4.f;
    umin[tr] = fminf(fminf(ur[tr][0], ur[tr][1]), fminf(ur[tr][2], ur[tr][3]));
  }
  int cbase = seg * 256;
  float vc_cur[4], vc_nxt[4];
#pragma unroll
  for (int tc = 0; tc < 4; ++tc) vc_cur[tc] = 0.5f * sqb[cbase + tc * 16 + arow];

  // swizzled LDS writes (conflict-free Latin square on bank groups)
#pragma unroll
  for (int k = 0; k < 8; ++k) {
    int c = t + k * 256;
    int r = c >> 3;
    sB[r * 8 + ((c & 7) ^ (r & 7))] = v[k];
  }
  __syncthreads();   // the ONLY barrier

  int a7 = arow & 7;
#pragma unroll 1
  for (int cc = 0; cc < 4; ++cc) {
    int c0 = cbase + cc * 64;
    // prefetch next cc's column-sq (valid dummy addr for cc==3)
    int nx = (cc < 3) ? (cc + 1) : 0;
#pragma unroll
    for (int tc = 0; tc < 4; ++tc)
      vc_nxt[tc] = 0.5f * sqb[cbase + nx * 64 + tc * 16 + arow];

#pragma unroll
    for (int tc = 0; tc < 4; ++tc) {
      int rl = cc * 64 + tc * 16 + arow;
      short8 b0 = *(const short8*)&sB[rl * 8 + (q ^ a7)];
      short8 b1 = *(const short8*)&sB[rl * 8 + ((q + 4) ^ a7)];
      float vct = vc_cur[tc];
      f32x4 acc[4];
#pragma unroll
      for (int tr = 0; tr < 4; ++tr) {
        f32x4 z = {0.f, 0.f, 0.f, 0.f};
        f32x4 t0 = __builtin_amdgcn_mfma_f32_16x16x32_bf16(afrag[tr][0], b0, z, 0, 0, 0);
        acc[tr] = __builtin_amdgcn_mfma_f32_16x16x32_bf16(afrag[tr][1], b1, t0, 0, 0, 0);
      }
      float cm = -1.f;
#pragma unroll
      for (int tr = 0; tr < 4; ++tr) {
        f32x4 a = acc[tr];
        float m = fmaxf(fmaxf(a[0], a[1]), fmaxf(a[2], a[3]));
        cm = fmaxf(cm, m - (umin[tr] + vct));
      }
      if (__ballot(cm > 0.f)) {
#pragma unroll
        for (int tr = 0; tr < 4; ++tr)
#pragma unroll
          for (int rg = 0; rg < 4; ++rg) {
            float g = acc[tr][rg];
            float th = ur[tr][rg] + vct;
            if (g > th) {
              float d2 = 2.f * (th - g) + 8.f;   // = sq_r + sq_c - 2g  (< 8)
              int rowpt = rowbase + tr * 16 + (q << 2) + rg;
              int colpt = c0 + tc * 16 + arow;
              int gr = b * NPTS + rowpt;
              union { float f; unsigned u; } cv; cv.f = d2 + 16.f;  // monotone bits
              unsigned key = (cv.u & 0xFFFFE000u) | (unsigned)colpt;
              unsigned slot = atomicAdd(&cnt[gr], 1u);
              if (slot < CAP) cand[gr * CAP + slot] = key;
            }
          }
      }
    }
#pragma unroll
    for (int tc = 0; tc < 4; ++tc) vc_cur[tc] = vc_nxt[tc];
  }
}

// ---------------- K3: refine (only rows with >1 candidate) ----------------
__global__ __launch_bounds__(256) void k3_refine(
    const float* __restrict__ f32f, const float* __restrict__ sq,
    const unsigned* __restrict__ cnt, const unsigned* __restrict__ cand,
    float* __restrict__ W, int* __restrict__ IDX) {
  int r = blockIdx.x * 256 + threadIdx.x;  // 64 blocks
  int b = r >> 13;
  unsigned count = cnt[r];
  if (count > CAP) count = CAP;
  if (count <= 1) return;                  // self-only: K4 fast path handles it

  unsigned k[CAP];
#pragma unroll
  for (int j = 0; j < CAP; ++j)
    k[j] = (j < (int)count) ? cand[r * CAP + j] : 0xFFFFFFFFu;
#pragma unroll
  for (int a = 0; a < CAP - 1; ++a)
#pragma unroll
    for (int c = 0; c < CAP - 1; ++c) {
      unsigned lo = min(k[c], k[c + 1]);
      unsigned hi = max(k[c], k[c + 1]);
      k[c] = lo; k[c + 1] = hi;
    }

  float fr[64];
  const f32x4* fr4 = (const f32x4*)(f32f + (size_t)r * 64);
#pragma unroll
  for (int j = 0; j < 16; ++j) {
    f32x4 v = fr4[j];
    fr[4 * j] = v[0]; fr[4 * j + 1] = v[1]; fr[4 * j + 2] = v[2]; fr[4 * j + 3] = v[3];
  }
  float sqr = sq[r];
  int nsel = (int)count < KNB ? (int)count : KNB;
#pragma unroll
  for (int kk = 0; kk < KNB; ++kk) {
    float w = 0.f;
    int gi = r;
    if (kk < nsel) {
      int col = (int)(k[kk] & 8191u);
      gi = b * NPTS + col;
      const float* fm = f32f + (size_t)gi * 64;
      float dot = 0.f;
#pragma unroll
      for (int d = 0; d < 64; ++d) dot = fmaf(fr[d], fm[d], dot);
      float d2 = sqr + sq[gi] - 2.f * dot;  // self -> exactly 0 -> w = 1
      w = expf(-d2);
    }
    W[r * KNB + kk] = w;
    IDX[r * KNB + kk] = gi;
  }
}

// ---------------- K4: single block, q in LDS, 5 iterations with __syncthreads ----------------
__global__ __launch_bounds__(1024) void k4_fused(
    const float* __restrict__ logits, const unsigned* __restrict__ cnt,
    const float* __restrict__ W, const int* __restrict__ IDX,
    float* __restrict__ out) {
  __shared__ float qs[NTOT];                // 64 KB
  int t = threadIdx.x;
  float lg[16], u[16];
  unsigned c[16];
#pragma unroll
  for (int j = 0; j < 16; ++j) {
    int i = j * 1024 + t;
    lg[j] = logits[i];
    c[j] = cnt[i];
    u[j] = lg[j];
    qs[i] = 1.f / (1.f + expf(-u[j]));
  }
  __syncthreads();
  for (int it = 0; it < 5; ++it) {
#pragma unroll
    for (int j = 0; j < 16; ++j) {
      int i = j * 1024 + t;
      float msg;
      if (c[j] <= 1u) {
        msg = qs[i];                         // self weight is exactly 1
      } else {
        msg = 0.f;
        const float* wp = W + (size_t)i * KNB;
        const int* ip = IDX + (size_t)i * KNB;
#pragma unroll
        for (int kk = 0; kk < KNB; ++kk) msg = fmaf(wp[kk], qs[ip[kk]], msg);
      }
      u[j] = lg[j] - msg;
    }
    __syncthreads();                         // all qs reads done
#pragma unroll
    for (int j = 0; j < 16; ++j) {
      int i = j * 1024 + t;
      qs[i] = 1.f / (1.f + expf(-u[j]));
    }
    __syncthreads();                         // writes visible
  }
#pragma unroll
  for (int j = 0; j < 16; ++j) {
    int i = j * 1024 + t;
    out[i] = 1.f / (1.f + expf(-u[j]));
  }
}

// ---------------- launch ----------------
extern "C" void kernel_launch(void* const* d_in, const int* in_sizes, int n_in,
                              void* d_out, int out_size, void* d_ws, size_t ws_size,
                              hipStream_t stream) {
  const float* logits = (const float*)d_in[0]; // [2][8192]
  const float* p      = (const float*)d_in[1]; // [2][64][8192]
  const float* W1     = (const float*)d_in[2];
  const float* b1     = (const float*)d_in[3];
  const float* W2     = (const float*)d_in[4];
  const float* b2     = (const float*)d_in[5];
  float* out = (float*)d_out;                  // [2][8192]

  char* ws = (char*)d_ws;
  float* W12 = (float*)ws;                              // 4096 f
  float* b12 = W12 + 4096;                              // 64 f
  float* f32f = b12 + 64;                               // NTOT*64 f
  unsigned short* fbf = (unsigned short*)(f32f + (size_t)NTOT * 64); // NTOT*64 bf16
  float* sq = (float*)(fbf + (size_t)NTOT * 64);        // NTOT f
  unsigned* cnt = (unsigned*)(sq + NTOT);               // NTOT u32
  unsigned* cand = cnt + NTOT;                          // NTOT*CAP u32
  float* Wbuf = (float*)(cand + (size_t)NTOT * CAP);    // NTOT*11 f
  int* IDX = (int*)(Wbuf + (size_t)NTOT * KNB);         // NTOT*11 i32

  k0_w12<<<16, 256, 0, stream>>>(W1, b1, W2, b2, W12, b12);
  k1_encode<<<256, 256, 0, stream>>>(p, W12, b12, f32f, fbf, sq, cnt);
  k2_gram_select<<<2048, 256, 0, stream>>>(fbf, sq, cnt, cand);
  k3_refine<<<64, 256, 0, stream>>>(f32f, sq, cnt, cand, Wbuf, IDX);
  k4_fused<<<1, 1024, 0, stream>>>(logits, cnt, Wbuf, IDX, out);
}

// Round 4
// 133.430 us; speedup vs baseline: 1.3150x; 1.0805x over previous
//
#include <hip/hip_runtime.h>

#define NPTS 8192
#define NTOT 16384
#define KNB 11
#define CAP 16
#define MARG 9.0f

typedef __attribute__((ext_vector_type(8))) short short8;
typedef __attribute__((ext_vector_type(4))) float f32x4;

__device__ __forceinline__ unsigned short f2bf(float x) {
  union { float f; unsigned u; } v; v.f = x;
  unsigned r = v.u + 0x7FFFu + ((v.u >> 16) & 1u);
  return (unsigned short)(r >> 16);
}

__device__ __forceinline__ float sigm(float x) { return 1.f / (1.f + expf(-x)); }

// ---------------- K1: fused W12=W1*W2 (per-block, LDS) + encode ----------------
// 256 blocks x 512 threads. Block handles 64 points; wave w handles dims e0=w*8..+8.
__global__ __launch_bounds__(512) void k1_encode(
    const float* __restrict__ p,      // [2][64][NPTS]
    const float* __restrict__ W1, const float* __restrict__ b1,
    const float* __restrict__ W2, const float* __restrict__ b2,
    float* __restrict__ f32f,         // [NTOT][64]
    unsigned short* __restrict__ fpre,// [NTOT][32] bf16 (dims 0..31)
    float* __restrict__ sq,           // [NTOT] full 64-dim |f|^2
    float* __restrict__ sq32,         // [NTOT] dims 0..31 |f|^2
    unsigned* __restrict__ cnt) {     // [NTOT]
  __shared__ float sW1[64 * 65];     // padded (+1) to break bank conflicts
  __shared__ float sW2[64 * 64];
  __shared__ float sW12[64 * 64];
  __shared__ float sb[64];
  __shared__ float sPart[8][64];
  int t = threadIdx.x;
  int gid = blockIdx.x * 512 + t;
  if (gid < NTOT) cnt[gid] = 0u;

  for (int i = t; i < 4096; i += 512) {
    sW1[(i >> 6) * 65 + (i & 63)] = W1[i];
    sW2[i] = W2[i];
  }
  __syncthreads();

  {
    int d = t >> 3, e0c = (t & 7) * 8;
    float a8[8];
#pragma unroll
    for (int j = 0; j < 8; ++j) a8[j] = 0.f;
    for (int k = 0; k < 64; ++k) {
      float a = sW1[d * 65 + k];
#pragma unroll
      for (int j = 0; j < 8; ++j)
        a8[j] = fmaf(a, sW2[k * 64 + e0c + j], a8[j]);
    }
#pragma unroll
    for (int j = 0; j < 8; ++j) sW12[d * 64 + e0c + j] = a8[j];
  }
  if (t < 64) {
    float sbv = b2[t];
    for (int k = 0; k < 64; ++k) sbv = fmaf(b1[k], sW2[k * 64 + t], sbv);
    sb[t] = sbv;
  }
  __syncthreads();

  int lane = t & 63;
  int w = __builtin_amdgcn_readfirstlane(t >> 6);
  int e0 = w * 8;
  int base = blockIdx.x * 64;
  int b = base >> 13, n0 = base & (NPTS - 1);
  const float* pb = p + (size_t)b * 64 * NPTS + n0 + lane;

  float f[8];
#pragma unroll
  for (int j = 0; j < 8; ++j) f[j] = sb[e0 + j];
#pragma unroll 8
  for (int d = 0; d < 64; ++d) {
    float pd = pb[(size_t)d * NPTS];
#pragma unroll
    for (int j = 0; j < 8; ++j)
      f[j] = fmaf(pd, sW12[d * 64 + e0 + j], f[j]);
  }
  float s = 0.f;
#pragma unroll
  for (int j = 0; j < 8; ++j) s = fmaf(f[j], f[j], s);
  sPart[w][lane] = s;
  __syncthreads();
  if (w == 0) {
    float s32 = (sPart[0][lane] + sPart[1][lane]) + (sPart[2][lane] + sPart[3][lane]);
    float s64 = s32 + ((sPart[4][lane] + sPart[5][lane]) + (sPart[6][lane] + sPart[7][lane]));
    sq32[base + lane] = s32;
    sq[base + lane] = s64;
  }
  f32x4* o4 = (f32x4*)(f32f + (size_t)(base + lane) * 64 + e0);
  { f32x4 v0; v0[0]=f[0]; v0[1]=f[1]; v0[2]=f[2]; v0[3]=f[3]; o4[0]=v0;
    f32x4 v1; v1[0]=f[4]; v1[1]=f[5]; v1[2]=f[6]; v1[3]=f[7]; o4[1]=v1; }
  if (w < 4) {
    unsigned* ob = (unsigned*)(fpre + (size_t)(base + lane) * 32 + e0);
#pragma unroll
    for (int jj = 0; jj < 4; ++jj) {
      unsigned lo = f2bf(f[2 * jj]);
      unsigned hi = f2bf(f[2 * jj + 1]);
      ob[jj] = lo | (hi << 16);
    }
  }
}

// ---------------- K2: 32-dim prefilter Gram, triangle-symmetric, 2-pass capture ----
// 1056 blocks = 2 x 528 (lower-triangle incl diag of 32x32 256-blocks).
// Hot: 1 MFMA/tile (K=32), min-scan only. Cold pass-2 (per wave, rare): recompute + capture.
__global__ __launch_bounds__(256) void k2_gram_select(
    const unsigned short* __restrict__ fpre, // [NTOT][32]
    const float* __restrict__ sq32,          // [NTOT]
    unsigned* __restrict__ cnt,              // [NTOT]
    unsigned* __restrict__ cand) {           // [NTOT][CAP]
  __shared__ uint4 sB[1024];                 // 16 KB panel, XOR-swizzled
  int bid = blockIdx.x;
  int b = (bid >= 528) ? 1 : 0;
  int rem = bid - b * 528;
  int band = (int)((sqrtf(8.f * (float)rem + 1.f) - 1.f) * 0.5f);
  if (((band + 1) * (band + 2)) / 2 <= rem) band++;
  else if ((band * (band + 1)) / 2 > rem) band--;
  int seg = rem - (band * (band + 1)) / 2;

  int t = threadIdx.x;
  int lane = t & 63, wave = t >> 6;
  int arow = lane & 15;
  int q = lane >> 4;
  int rowbase = band * 256 + wave * 64;
  int cbase = seg * 256;
  const unsigned short* fb = fpre + (size_t)b * NPTS * 32;
  const float* s32b = sq32 + b * NPTS;

  // ---- prologue: all global loads, then ONE barrier ----
  const uint4* gsrc = (const uint4*)fb + (size_t)seg * 1024;
  uint4 v[4];
#pragma unroll
  for (int k = 0; k < 4; ++k) v[k] = gsrc[t + k * 256];

  short8 afrag[4];
#pragma unroll
  for (int tr = 0; tr < 4; ++tr)
    afrag[tr] = *(const short8*)(fb + (size_t)(rowbase + tr * 16 + arow) * 32 + q * 8);

  f32x4 srq[4];
  float hs0, hs1, hs2, hs3;
#pragma unroll
  for (int tr = 0; tr < 4; ++tr)
    srq[tr] = *(const f32x4*)(s32b + rowbase + tr * 16 + (q << 2));
  hs0 = 0.5f * fminf(fminf(srq[0][0], srq[0][1]), fminf(srq[0][2], srq[0][3]));
  hs1 = 0.5f * fminf(fminf(srq[1][0], srq[1][1]), fminf(srq[1][2], srq[1][3]));
  hs2 = 0.5f * fminf(fminf(srq[2][0], srq[2][1]), fminf(srq[2][2], srq[2][3]));
  hs3 = 0.5f * fminf(fminf(srq[3][0], srq[3][1]), fminf(srq[3][2], srq[3][3]));

  float scq[16];
#pragma unroll
  for (int cc = 0; cc < 4; ++cc)
#pragma unroll
    for (int tc = 0; tc < 4; ++tc)
      scq[cc * 4 + tc] = s32b[cbase + cc * 64 + tc * 16 + arow];

#pragma unroll
  for (int k = 0; k < 4; ++k) {
    int c = t + k * 256;
    int r = c >> 2, qq = c & 3;
    sB[r * 4 + (qq ^ (r & 3))] = v[k];
  }
  __syncthreads();   // the ONLY barrier

  // ---- hot pass: MFMA + min-scan, no captures ----
  f32x4 z4 = {0.f, 0.f, 0.f, 0.f};
  float cm = -1e30f;
#pragma unroll
  for (int cc = 0; cc < 4; ++cc)
#pragma unroll
    for (int tc = 0; tc < 4; ++tc) {
      int rl = cc * 64 + tc * 16 + arow;
      short8 bf = *(const short8*)&sB[rl * 4 + (q ^ (rl & 3))];
      f32x4 a0 = __builtin_amdgcn_mfma_f32_16x16x32_bf16(afrag[0], bf, z4, 0, 0, 0);
      f32x4 a1 = __builtin_amdgcn_mfma_f32_16x16x32_bf16(afrag[1], bf, z4, 0, 0, 0);
      f32x4 a2 = __builtin_amdgcn_mfma_f32_16x16x32_bf16(afrag[2], bf, z4, 0, 0, 0);
      f32x4 a3 = __builtin_amdgcn_mfma_f32_16x16x32_bf16(afrag[3], bf, z4, 0, 0, 0);
      float t0 = fmaxf(fmaxf(a0[0], a0[1]), fmaxf(a0[2], a0[3])) - hs0;
      float t1 = fmaxf(fmaxf(a1[0], a1[1]), fmaxf(a1[2], a1[3])) - hs1;
      float t2 = fmaxf(fmaxf(a2[0], a2[1]), fmaxf(a2[2], a2[3])) - hs2;
      float t3 = fmaxf(fmaxf(a3[0], a3[1]), fmaxf(a3[2], a3[3])) - hs3;
      float m = fmaxf(fmaxf(t0, t1), fmaxf(t2, t3));
      cm = fmaxf(cm, m - 0.5f * scq[cc * 4 + tc]);
    }

  // ---- cold pass-2 (per wave): recompute tiles, exact-threshold capture + mirror ----
  if (__ballot(cm > -0.5f * MARG)) {
#pragma unroll 1
    for (int cc = 0; cc < 4; ++cc)
#pragma unroll 1
      for (int tc = 0; tc < 4; ++tc) {
        int rl = cc * 64 + tc * 16 + arow;
        short8 bf = *(const short8*)&sB[rl * 4 + (q ^ (rl & 3))];
        int colpt = cbase + cc * 64 + tc * 16 + arow;
        float scv = s32b[colpt];
#pragma unroll
        for (int tr = 0; tr < 4; ++tr) {
          f32x4 a = __builtin_amdgcn_mfma_f32_16x16x32_bf16(afrag[tr], bf, z4, 0, 0, 0);
#pragma unroll
          for (int rg = 0; rg < 4; ++rg) {
            float d2 = srq[tr][rg] + scv - 2.f * a[rg];
            if (d2 < MARG) {
              int rowpt = rowbase + tr * 16 + (q << 2) + rg;
              int gr = b * NPTS + rowpt;
              union { float f; unsigned u; } cv; cv.f = d2 + 16.f;  // monotone bits
              unsigned kb = cv.u & 0xFFFFE000u;
              unsigned slot = atomicAdd(&cnt[gr], 1u);
              if (slot < CAP) cand[gr * CAP + slot] = kb | (unsigned)colpt;
              if (band != seg) {
                int gc = b * NPTS + colpt;
                unsigned slot2 = atomicAdd(&cnt[gc], 1u);
                if (slot2 < CAP) cand[gc * CAP + slot2] = kb | (unsigned)rowpt;
              }
            }
          }
        }
      }
  }
}

// ---------------- K3: refine (only rows with >1 candidate), exact f32 ----------------
__global__ __launch_bounds__(256) void k3_refine(
    const float* __restrict__ f32f, const float* __restrict__ sq,
    const unsigned* __restrict__ cnt, const unsigned* __restrict__ cand,
    float* __restrict__ W, int* __restrict__ IDX) {
  int r = blockIdx.x * 256 + threadIdx.x;  // 64 blocks
  int b = r >> 13;
  unsigned count = cnt[r];
  if (count > CAP) count = CAP;
  if (count <= 1) return;                  // self-only: K4 fast path handles it

  unsigned k[CAP];
#pragma unroll
  for (int j = 0; j < CAP; ++j)
    k[j] = (j < (int)count) ? cand[r * CAP + j] : 0xFFFFFFFFu;
#pragma unroll
  for (int a = 0; a < CAP - 1; ++a)
#pragma unroll
    for (int c = 0; c < CAP - 1; ++c) {
      unsigned lo = min(k[c], k[c + 1]);
      unsigned hi = max(k[c], k[c + 1]);
      k[c] = lo; k[c + 1] = hi;
    }

  float fr[64];
  const f32x4* fr4 = (const f32x4*)(f32f + (size_t)r * 64);
#pragma unroll
  for (int j = 0; j < 16; ++j) {
    f32x4 v = fr4[j];
    fr[4 * j] = v[0]; fr[4 * j + 1] = v[1]; fr[4 * j + 2] = v[2]; fr[4 * j + 3] = v[3];
  }
  float sqr = sq[r];
  int nsel = (int)count < KNB ? (int)count : KNB;
#pragma unroll
  for (int kk = 0; kk < KNB; ++kk) {
    float w = 0.f;
    int gi = r;
    if (kk < nsel) {
      int col = (int)(k[kk] & 8191u);
      gi = b * NPTS + col;
      const float* fm = f32f + (size_t)gi * 64;
      float dot = 0.f;
#pragma unroll
      for (int d = 0; d < 64; ++d) dot = fmaf(fr[d], fm[d], dot);
      float d2 = sqr + sq[gi] - 2.f * dot;
      w = expf(-d2);
    }
    W[r * KNB + kk] = w;
    IDX[r * KNB + kk] = gi;
  }
}

// ---------------- K4: per-batch block, q in LDS, 5 iterations ----------------
__global__ __launch_bounds__(1024) void k4_fused(
    const float* __restrict__ logits, const unsigned* __restrict__ cnt,
    const float* __restrict__ W, const int* __restrict__ IDX,
    float* __restrict__ out) {
  __shared__ float qs[NPTS];                // 32 KB
  int t = threadIdx.x;
  int rb = blockIdx.x * NPTS;
  float lg[8], u[8];
  unsigned c[8];
#pragma unroll
  for (int j = 0; j < 8; ++j) {
    int il = j * 1024 + t;
    lg[j] = logits[rb + il];
    c[j] = cnt[rb + il];
    u[j] = lg[j];
    qs[il] = sigm(u[j]);
  }
  __syncthreads();
  for (int it = 0; it < 5; ++it) {
#pragma unroll
    for (int j = 0; j < 8; ++j) {
      int il = j * 1024 + t;
      float msg;
      if (c[j] <= 1u) {
        msg = qs[il];                        // self weight is exactly 1
      } else {
        msg = 0.f;
        const float* wp = W + (size_t)(rb + il) * KNB;
        const int* ip = IDX + (size_t)(rb + il) * KNB;
#pragma unroll
        for (int kk = 0; kk < KNB; ++kk) msg = fmaf(wp[kk], qs[ip[kk] - rb], msg);
      }
      u[j] = lg[j] - msg;
    }
    __syncthreads();
#pragma unroll
    for (int j = 0; j < 8; ++j) qs[j * 1024 + t] = sigm(u[j]);
    __syncthreads();
  }
#pragma unroll
  for (int j = 0; j < 8; ++j) out[rb + j * 1024 + t] = sigm(u[j]);
}

// ---------------- launch ----------------
extern "C" void kernel_launch(void* const* d_in, const int* in_sizes, int n_in,
                              void* d_out, int out_size, void* d_ws, size_t ws_size,
                              hipStream_t stream) {
  const float* logits = (const float*)d_in[0]; // [2][8192]
  const float* p      = (const float*)d_in[1]; // [2][64][8192]
  const float* W1     = (const float*)d_in[2];
  const float* b1     = (const float*)d_in[3];
  const float* W2     = (const float*)d_in[4];
  const float* b2     = (const float*)d_in[5];
  float* out = (float*)d_out;                  // [2][8192]

  char* ws = (char*)d_ws;
  float* f32f = (float*)ws;                                        // NTOT*64 f
  unsigned short* fpre = (unsigned short*)(f32f + (size_t)NTOT * 64); // NTOT*32 bf16
  float* sq = (float*)(fpre + (size_t)NTOT * 32);                  // NTOT f
  float* sq32 = sq + NTOT;                                         // NTOT f
  unsigned* cnt = (unsigned*)(sq32 + NTOT);                        // NTOT u32
  unsigned* cand = cnt + NTOT;                                     // NTOT*CAP u32
  float* Wbuf = (float*)(cand + (size_t)NTOT * CAP);               // NTOT*11 f
  int* IDX = (int*)(Wbuf + (size_t)NTOT * KNB);                    // NTOT*11 i32

  k1_encode<<<256, 512, 0, stream>>>(p, W1, b1, W2, b2, f32f, fpre, sq, sq32, cnt);
  k2_gram_select<<<1056, 256, 0, stream>>>(fpre, sq32, cnt, cand);
  k3_refine<<<64, 256, 0, stream>>>(f32f, sq, cnt, cand, Wbuf, IDX);
  k4_fused<<<2, 1024, 0, stream>>>(logits, cnt, Wbuf, IDX, out);
}